// Round 4
// baseline (332.178 us; speedup 1.0000x reference)
//
#include <hip/hip_runtime.h>
#include <math.h>

typedef __attribute__((ext_vector_type(8))) short short8;
typedef __attribute__((ext_vector_type(4))) float f32x4;
typedef __attribute__((ext_vector_type(16))) float f32x16;
typedef __attribute__((ext_vector_type(4))) int int32x4;
typedef unsigned short bf16_t;

#define GLOAD_LDS16(g, l)                                                   \
    __builtin_amdgcn_global_load_lds(                                       \
        (__attribute__((address_space(1))) void*)(g),                       \
        (__attribute__((address_space(3))) void*)(l), 16, 0, 0)

__device__ __forceinline__ bf16_t f2b_rne(float f) {
    unsigned int u = __float_as_uint(f);
    u += 0x7FFFu + ((u >> 16) & 1u);
    return (bf16_t)(u >> 16);
}

__device__ __forceinline__ void store_out(bf16_t* p, float v) { *p = f2b_rne(v); }
__device__ __forceinline__ void store_out(float* p, float v) { *p = v; }

// ---------------------------------------------------------------------------
// fp32 -> bf16 conversion
// ---------------------------------------------------------------------------
__global__ __launch_bounds__(256) void f2b_kernel(const float* __restrict__ in,
                                                  bf16_t* __restrict__ out, int n4) {
    int stride = gridDim.x * 256;
    for (int i = blockIdx.x * 256 + threadIdx.x; i < n4; i += stride) {
        float4 v = ((const float4*)in)[i];
        ushort4 p;
        p.x = f2b_rne(v.x); p.y = f2b_rne(v.y);
        p.z = f2b_rne(v.z); p.w = f2b_rne(v.w);
        ((ushort4*)out)[i] = p;
    }
}

// ---------------------------------------------------------------------------
// Relative-position bias table: tab[h][(k-q)+1023]  (validated in round 2)
// ---------------------------------------------------------------------------
__global__ void build_bias_tab(const float* __restrict__ emb, float* __restrict__ tab) {
    int idx = blockIdx.x * 256 + threadIdx.x;
    if (idx >= 2047) return;
    int rel = idx - 1023;
    int rb = rel > 0 ? 16 : 0;
    int rp = rel < 0 ? -rel : rel;
    int bucket;
    if (rp < 8) {
        bucket = rb + rp;
    } else {
        float t = logf((float)rp * 0.125f);
        int vi = 8 + (int)(t / 2.772588722239781f * 8.0f);
        bucket = rb + (vi < 15 ? vi : 15);
    }
    #pragma unroll
    for (int hh = 0; hh < 16; hh++)
        tab[hh * 2048 + idx] = emb[bucket * 16 + hh];
}

// ---------------------------------------------------------------------------
// bf16 MFMA GEMM (m97 structure, unchanged — passed round 2)
// ---------------------------------------------------------------------------
template <typename OT>
__global__ __launch_bounds__(256) void gemm_mfma(const bf16_t* __restrict__ A,
                                                 const bf16_t* __restrict__ B,
                                                 OT* __restrict__ C, int N) {
    __shared__ __align__(16) bf16_t As[128 * 32];
    __shared__ __align__(16) bf16_t Bs[128 * 32];
    const int tid = threadIdx.x;
    const int lane = tid & 63;
    const int wv = tid >> 6;
    const int wr = wv >> 1, wc = wv & 1;
    const int m0 = blockIdx.y * 128, n0 = blockIdx.x * 128;
    const int cc = lane & 15, cg = lane >> 4;

    f32x4 acc[4][4];
    #pragma unroll
    for (int i = 0; i < 4; i++)
        #pragma unroll
        for (int j = 0; j < 4; j++) acc[i][j] = {0.f, 0.f, 0.f, 0.f};

    for (int k0 = 0; k0 < 1024; k0 += 32) {
        __syncthreads();
        #pragma unroll
        for (int it = 0; it < 2; it++) {
            int c = it * 256 + tid;
            int r = c >> 2, kc = (c & 3) * 8;
            GLOAD_LDS16(A + (size_t)(m0 + r) * 1024 + k0 + kc, &As[c * 8]);
            GLOAD_LDS16(B + (size_t)(n0 + r) * 1024 + k0 + kc, &Bs[c * 8]);
        }
        __syncthreads();

        short8 af[4], bf[4];
        #pragma unroll
        for (int mf = 0; mf < 4; mf++)
            af[mf] = *(const short8*)&As[(wr * 64 + mf * 16 + cc) * 32 + cg * 8];
        #pragma unroll
        for (int nf = 0; nf < 4; nf++)
            bf[nf] = *(const short8*)&Bs[(wc * 64 + nf * 16 + cc) * 32 + cg * 8];
        #pragma unroll
        for (int mf = 0; mf < 4; mf++)
            #pragma unroll
            for (int nf = 0; nf < 4; nf++)
                acc[mf][nf] = __builtin_amdgcn_mfma_f32_16x16x32_bf16(
                    af[mf], bf[nf], acc[mf][nf], 0, 0, 0);
    }

    #pragma unroll
    for (int mf = 0; mf < 4; mf++)
        #pragma unroll
        for (int j = 0; j < 4; j++) {
            size_t row = (size_t)(m0 + wr * 64 + mf * 16 + cg * 4 + j);
            OT* cp = C + row * N + n0 + wc * 64 + cc;
            #pragma unroll
            for (int nf = 0; nf < 4; nf++) store_out(cp + nf * 16, acc[mf][nf][j]);
        }
}

// ---------------------------------------------------------------------------
// V transpose: qkv V-part [B,S,3072] -> vt [B,H,64,1024]
// ---------------------------------------------------------------------------
__global__ __launch_bounds__(256) void transpose_v(const bf16_t* __restrict__ qkv,
                                                   bf16_t* __restrict__ vt) {
    const int tid = threadIdx.x;
    const int d = tid & 63, so = tid >> 6;
    const int s0 = blockIdx.x * 32 + so * 8;
    const int h = blockIdx.y, b = blockIdx.z;
    const bf16_t* src = qkv + (size_t)(b * 1024 + s0) * 3072 + 2048 + h * 64 + d;
    short8 v;
    #pragma unroll
    for (int j = 0; j < 8; j++) v[j] = (short)src[(size_t)j * 3072];
    *(short8*)(vt + ((size_t)(b * 16 + h) * 64 + d) * 1024 + s0) = v;
}

// ---------------------------------------------------------------------------
// Swapped-operand MFMA flash attention (T12 structure).
// Grid (8 q-chunks, 16 heads, 8 batch), 256 thr / 4 waves; wave owns 32 q.
// S^T = mfma(Kfrag, Qfrag) -> lane holds P-row for q = lane&31.
// In-register softmax; P packed via v_cvt_pk_bf16_f32 + shfl_xor(32).
// O^T = mfma(Vt-frag, Pfrag). No __syncthreads in the k-loop.
// ---------------------------------------------------------------------------
__global__ __launch_bounds__(256, 4) void attn_mfma2(const bf16_t* __restrict__ qkv,
                                                     const float* __restrict__ tab,
                                                     const bf16_t* __restrict__ vt,
                                                     bf16_t* __restrict__ attn_out) {
    __shared__ float bias2[2304];
    __shared__ bf16_t Ol[4 * 32 * 68];

    const int tid = threadIdx.x;
    const int lane = tid & 63;
    const int w = tid >> 6;
    const int l31 = lane & 31;
    const int hi = lane >> 5;
    const int q0 = blockIdx.x * 128;
    const int h = blockIdx.y, b = blockIdx.z;

    const float* tabh = tab + h * 2048;
    const int wbase = 896 - q0;
    #pragma unroll
    for (int it = 0; it < 5; it++) {
        int j = it * 256 + tid;
        if (j < 1151) {
            bias2[2 * j]     = tabh[wbase + j];
            bias2[2 * j + 1] = tabh[wbase + j + 1];
        }
    }

    const size_t rs = 3072;
    const bf16_t* Qg = qkv + (size_t)b * 1024 * rs + h * 64;
    const bf16_t* Kg = Qg + 1024;
    const bf16_t* vth = vt + (size_t)(b * 16 + h) * 64 * 1024;

    const int qloc = w * 32 + l31;
    short8 qf[4];
    #pragma unroll
    for (int s = 0; s < 4; s++)
        qf[s] = *(const short8*)(Qg + (size_t)(q0 + qloc) * rs + 8 * hi + 16 * s);

    f32x16 O0 = (f32x16)0.f, O1 = (f32x16)0.f;
    float m_run = -1e30f, l_run = 0.f;

    __syncthreads();  // bias2 ready

    for (int k0 = 0; k0 < 1024; k0 += 32) {
        // QK^T (swapped): S^T[kk][q]
        const bf16_t* krow = Kg + (size_t)(k0 + l31) * rs + 8 * hi;
        f32x16 S = (f32x16)0.f;
        #pragma unroll
        for (int s = 0; s < 4; s++) {
            short8 kf = *(const short8*)(krow + 16 * s);
            S = __builtin_amdgcn_mfma_f32_32x32x16_bf16(kf, qf[s], S, 0, 0, 0);
        }

        // bias add: reg r -> kk = (r&3) + 8*(r>>2) + 4*hi
        float p[16];
        #pragma unroll
        for (int g = 0; g < 4; g++) {
            int bi = k0 + 8 * g + 4 * hi + 127 - qloc;
            float2 b0 = *(const float2*)&bias2[2 * bi];
            float2 b1 = *(const float2*)&bias2[2 * (bi + 2)];
            p[4 * g + 0] = S[4 * g + 0] + b0.x;
            p[4 * g + 1] = S[4 * g + 1] + b0.y;
            p[4 * g + 2] = S[4 * g + 2] + b1.x;
            p[4 * g + 3] = S[4 * g + 3] + b1.y;
        }

        // online softmax, lane-local stats, defer-max THR=8
        float pmax = p[0];
        #pragma unroll
        for (int r = 1; r < 16; r++) pmax = fmaxf(pmax, p[r]);
        pmax = fmaxf(pmax, __shfl_xor(pmax, 32));
        if (!__all(pmax - m_run <= 8.f)) {
            float mn = fmaxf(m_run, pmax);
            float sc = __expf(m_run - mn);
            l_run *= sc;
            #pragma unroll
            for (int r = 0; r < 16; r++) { O0[r] *= sc; O1[r] *= sc; }
            m_run = mn;
        }
        float rsum = 0.f;
        #pragma unroll
        for (int r = 0; r < 16; r++) { p[r] = __expf(p[r] - m_run); rsum += p[r]; }
        rsum += __shfl_xor(rsum, 32);
        l_run += rsum;

        // pack P to bf16; exchange partner halves to build PV B-frags
        unsigned int wv[8];
        #pragma unroll
        for (int i = 0; i < 8; i++) {
            unsigned int t;
            asm("v_cvt_pk_bf16_f32 %0, %1, %2" : "=v"(t) : "v"(p[2 * i]), "v"(p[2 * i + 1]));
            wv[i] = t;
        }
        unsigned int x0 = __shfl_xor(hi ? wv[0] : wv[2], 32);
        unsigned int x1 = __shfl_xor(hi ? wv[1] : wv[3], 32);
        unsigned int x2 = __shfl_xor(hi ? wv[4] : wv[6], 32);
        unsigned int x3 = __shfl_xor(hi ? wv[5] : wv[7], 32);
        int32x4 pf0i, pf1i;
        if (hi) {
            pf0i = (int32x4){(int)x0, (int)x1, (int)wv[2], (int)wv[3]};
            pf1i = (int32x4){(int)x2, (int)x3, (int)wv[6], (int)wv[7]};
        } else {
            pf0i = (int32x4){(int)wv[0], (int)wv[1], (int)x0, (int)x1};
            pf1i = (int32x4){(int)wv[4], (int)wv[5], (int)x2, (int)x3};
        }
        short8 pf0 = __builtin_bit_cast(short8, pf0i);
        short8 pf1 = __builtin_bit_cast(short8, pf1i);

        // PV (swapped): O^T[d][q] += Vt-frag x P-frag
        const bf16_t* vrow0 = vth + (size_t)l31 * 1024 + k0 + 8 * hi;
        const bf16_t* vrow1 = vth + (size_t)(32 + l31) * 1024 + k0 + 8 * hi;
        short8 vf;
        vf = *(const short8*)vrow0;
        O0 = __builtin_amdgcn_mfma_f32_32x32x16_bf16(vf, pf0, O0, 0, 0, 0);
        vf = *(const short8*)(vrow0 + 16);
        O0 = __builtin_amdgcn_mfma_f32_32x32x16_bf16(vf, pf1, O0, 0, 0, 0);
        vf = *(const short8*)vrow1;
        O1 = __builtin_amdgcn_mfma_f32_32x32x16_bf16(vf, pf0, O1, 0, 0, 0);
        vf = *(const short8*)(vrow1 + 16);
        O1 = __builtin_amdgcn_mfma_f32_32x32x16_bf16(vf, pf1, O1, 0, 0, 0);
    }

    // epilogue: normalize, LDS-bounce O^T -> row-major, coalesced stores
    float inv = 1.f / l_run;
    bf16_t* olw = &Ol[w * 32 * 68];
    #pragma unroll
    for (int r = 0; r < 16; r++) {
        int dr = (r & 3) + 8 * (r >> 2) + 4 * hi;
        olw[l31 * 68 + dr]      = f2b_rne(O0[r] * inv);
        olw[l31 * 68 + dr + 32] = f2b_rne(O1[r] * inv);
    }
    bf16_t* outp = attn_out + (size_t)(b * 1024 + q0 + w * 32) * 1024 + h * 64;
    #pragma unroll 4
    for (int i = 0; i < 32; i++)
        outp[(size_t)i * 1024 + lane] = olw[i * 68 + lane];
}

// ---------------------------------------------------------------------------
extern "C" void kernel_launch(void* const* d_in, const int* in_sizes, int n_in,
                              void* d_out, int out_size, void* d_ws, size_t ws_size,
                              hipStream_t stream) {
    const float* hs   = (const float*)d_in[0];  // [8,1024,1024]
    const float* wqkv = (const float*)d_in[1];  // [3072,1024]
    const float* emb  = (const float*)d_in[2];  // [32,16]
    const float* wout = (const float*)d_in[3];  // [1024,1024]
    float* out = (float*)d_out;                 // [8,1024,1024] fp32

    char* p = (char*)d_ws;
    bf16_t* qkvb  = (bf16_t*)p; p += (size_t)8192 * 3072 * 2;  // 48 MB
    bf16_t* attnb = (bf16_t*)p; p += (size_t)8192 * 1024 * 2;  // 16 MB
    bf16_t* hsb   = (bf16_t*)p; p += (size_t)8192 * 1024 * 2;  // 16 MB
    bf16_t* wqkvb = (bf16_t*)p; p += (size_t)3072 * 1024 * 2;  //  6 MB
    bf16_t* woutb = (bf16_t*)p; p += (size_t)1024 * 1024 * 2;  //  2 MB
    bf16_t* vtb   = (bf16_t*)p; p += (size_t)8 * 16 * 64 * 1024 * 2;  // 16 MB
    float*  tab   = (float*)p;                                 // 128 KB

    f2b_kernel<<<2048, 256, 0, stream>>>(hs, hsb, 8192 * 1024 / 4);
    f2b_kernel<<<768, 256, 0, stream>>>(wqkv, wqkvb, 3072 * 1024 / 4);
    f2b_kernel<<<256, 256, 0, stream>>>(wout, woutb, 1024 * 1024 / 4);
    build_bias_tab<<<8, 256, 0, stream>>>(emb, tab);

    gemm_mfma<bf16_t><<<dim3(3072 / 128, 8192 / 128), 256, 0, stream>>>(hsb, wqkvb, qkvb, 3072);
    transpose_v<<<dim3(32, 16, 8), 256, 0, stream>>>(qkvb, vtb);
    attn_mfma2<<<dim3(8, 16, 8), 256, 0, stream>>>(qkvb, tab, vtb, attnb);
    gemm_mfma<float><<<dim3(1024 / 128, 8192 / 128), 256, 0, stream>>>(attnb, woutb, out, 1024);
}